// Round 1
// baseline (22.765 us; speedup 1.0000x reference)
//
#include <hip/hip_runtime.h>
#include <hip/hip_bf16.h>

// Problem constants (fixed by the reference)
#define IN_DIM    128
#define OUT_DIM   64
#define NUM_BASIS 8
#define SEQ       512
#define BATCH     2
#define EPS       1e-5f

// ---------------------------------------------------------------------------
// Kernel A: per (b,s) row — x_trans = LN(x @ M^T)*gamma+beta, res = x @ Wres^T
// One wave (64 lanes) per row; lane o owns output channel o.
// ---------------------------------------------------------------------------
__global__ __launch_bounds__(64) void xform_ln_kernel(
    const float* __restrict__ x,     // (B*S, 128)
    const float* __restrict__ M,     // (64, 128)
    const float* __restrict__ Wres,  // (64, 128)
    const float* __restrict__ gamma, // (64)
    const float* __restrict__ beta,  // (64)
    float* __restrict__ xt,          // (B*S, 64) out
    float* __restrict__ res)         // (B*S, 64) out
{
    const int row = blockIdx.x;      // 0 .. B*S-1
    const int o   = threadIdx.x;     // 0 .. 63

    __shared__ float xs[IN_DIM];
    // cooperative load of the x row (64 lanes * float2 = 128 floats)
    reinterpret_cast<float2*>(xs)[o] =
        reinterpret_cast<const float2*>(x + (size_t)row * IN_DIM)[o];
    __syncthreads();

    const float4* x4 = reinterpret_cast<const float4*>(xs);
    const float4* m4 = reinterpret_cast<const float4*>(M + (size_t)o * IN_DIM);
    const float4* w4 = reinterpret_cast<const float4*>(Wres + (size_t)o * IN_DIM);

    float macc = 0.f, racc = 0.f;
#pragma unroll
    for (int c = 0; c < IN_DIM / 4; ++c) {
        float4 xv = x4[c];
        float4 mv = m4[c];
        float4 wv = w4[c];
        macc += xv.x * mv.x + xv.y * mv.y + xv.z * mv.z + xv.w * mv.w;
        racc += xv.x * wv.x + xv.y * wv.y + xv.z * wv.z + xv.w * wv.w;
    }

    // wave64 butterfly reduction: mean
    float s = macc;
#pragma unroll
    for (int off = 32; off > 0; off >>= 1) s += __shfl_xor(s, off);
    const float mu = s * (1.0f / OUT_DIM);

    // two-pass variance for accuracy
    const float d = macc - mu;
    float v = d * d;
#pragma unroll
    for (int off = 32; off > 0; off >>= 1) v += __shfl_xor(v, off);
    const float var = v * (1.0f / OUT_DIM);

    const float y = d * rsqrtf(var + EPS) * gamma[o] + beta[o];

    xt[(size_t)row * OUT_DIM + o]  = y;
    res[(size_t)row * OUT_DIM + o] = racc;
}

// ---------------------------------------------------------------------------
// Kernel B: one block per sequence position s.
//   W[s,i,j] = sum_g P[i,j,g] * cos(2*pi*k_s / (i*512 + j*8 + g + 2))
//   out[b,s,i] = sum_j xt[b,s,j] * W[s,i,j] + res[b,s,i]
// Thread layout: i = tid&63, grp = tid>>6 (4 groups), each group owns 16 j's.
// period flat-indexes as idx+2 -> inv period via v_rcp inline.
// cos(2*pi*t) == v_cos_f32(fract(t)) (hardware cos takes revolutions).
// ---------------------------------------------------------------------------
__global__ __launch_bounds__(256) void nk_kernel(
    const float* __restrict__ xt,        // (B*S, 64)
    const float* __restrict__ res,       // (B*S, 64)
    const float* __restrict__ P,         // (64, 64, 8)
    const int*   __restrict__ positions, // (S)
    float* __restrict__ out)             // (B, S, 64)
{
    const int s   = blockIdx.x;     // 0..511
    const int tid = threadIdx.x;
    const int i   = tid & 63;
    const int grp = tid >> 6;       // 0..3

    __shared__ float xts[BATCH][OUT_DIM];
    __shared__ float part[4][BATCH][OUT_DIM];

    if (tid < BATCH * OUT_DIM) {
        const int b = tid >> 6, j = tid & 63;
        xts[b][j] = xt[((size_t)b * SEQ + s) * OUT_DIM + j];
    }
    const float k = (float)positions[s];
    __syncthreads();

    float nk0 = 0.f, nk1 = 0.f;

#pragma unroll 4
    for (int jj = 0; jj < 16; ++jj) {
        const int j    = grp * 16 + jj;
        const int base = (i * OUT_DIM + j) * NUM_BASIS;   // flat (i,j,0)
        const float4* Pp = reinterpret_cast<const float4*>(P + base);
        const float4 p0 = Pp[0];
        const float4 p1 = Pp[1];
        const float basef = (float)(base + 2);            // period for g=0

        float w = 0.f;
        const float pv[8] = {p0.x, p0.y, p0.z, p0.w, p1.x, p1.y, p1.z, p1.w};
#pragma unroll
        for (int g = 0; g < NUM_BASIS; ++g) {
            const float period = basef + (float)g;                 // exact in f32
            const float inv    = __builtin_amdgcn_rcpf(period);    // ~1 ulp
            float t = k * inv;                                     // revolutions
            t = __builtin_amdgcn_fractf(t);                        // range-reduce
            w += pv[g] * __builtin_amdgcn_cosf(t);                 // cos(2*pi*t)
        }
        nk0 += xts[0][j] * w;
        nk1 += xts[1][j] * w;
    }

    part[grp][0][i] = nk0;
    part[grp][1][i] = nk1;
    __syncthreads();

    if (tid < BATCH * OUT_DIM) {
        const int b = tid >> 6, ii = tid & 63;
        const float sum = part[0][b][ii] + part[1][b][ii] +
                          part[2][b][ii] + part[3][b][ii];
        const size_t idx = ((size_t)b * SEQ + s) * OUT_DIM + ii;
        out[idx] = sum + res[idx];
    }
}

// ---------------------------------------------------------------------------
extern "C" void kernel_launch(void* const* d_in, const int* in_sizes, int n_in,
                              void* d_out, int out_size, void* d_ws, size_t ws_size,
                              hipStream_t stream)
{
    const float* x         = (const float*)d_in[0];
    const int*   positions = (const int*)d_in[1];
    const float* M         = (const float*)d_in[2];
    const float* P         = (const float*)d_in[3];
    const float* gamma     = (const float*)d_in[4];
    const float* beta      = (const float*)d_in[5];
    const float* Wres      = (const float*)d_in[6];
    float* out = (float*)d_out;

    float* xt  = (float*)d_ws;                    // (B*S*64) = 65536 floats
    float* res = xt + BATCH * SEQ * OUT_DIM;      // (B*S*64) = 65536 floats

    hipLaunchKernelGGL(xform_ln_kernel, dim3(BATCH * SEQ), dim3(64), 0, stream,
                       x, M, Wres, gamma, beta, xt, res);
    hipLaunchKernelGGL(nk_kernel, dim3(SEQ), dim3(256), 0, stream,
                       xt, res, P, positions, out);
}

// Round 2
// 21.303 us; speedup vs baseline: 1.0686x; 1.0686x over previous
//
#include <hip/hip_runtime.h>
#include <hip/hip_bf16.h>

// Problem constants (fixed by the reference)
#define IN_DIM    128
#define OUT_DIM   64
#define NUM_BASIS 8
#define SEQ       512
#define BATCH     2
#define EPS       1e-5f

// ---------------------------------------------------------------------------
// Fully fused: one block per sequence position s (512 blocks x 256 threads).
//
// Phase 1 (threads 0..127): for (b = tid>>6, o = tid&63):
//     xt[b][o] = LN(x[b,s,:] @ M[o,:]) * gamma + beta  (LN over o within wave)
//     rs[b][o] = x[b,s,:] @ Wres[o,:]
//   Wave 0 handles b=0, wave 1 handles b=1, so a 64-lane shfl butterfly
//   reduces exactly over the 64 output channels of one batch row.
//
// Phase 2 (all 256 threads): i = tid&63, grp = tid>>6 owns 16 j values:
//     W[i,j] = sum_g P[i,j,g] * cos(2*pi*k / ((i*64+j)*8 + g + 2))
//     nk[b][i] += xt[b][j] * W[i,j]
//   period flat-indexes as flat(i,j,g)+2 -> inverse via v_rcp_f32 inline;
//   cos(2*pi*t) == v_cos_f32(fract(t)) (hardware cos takes revolutions).
//
// Everything stays in LDS (~4KB); single launch, no ws round-trip.
// ---------------------------------------------------------------------------
__global__ __launch_bounds__(256) void fused_layerts_kernel(
    const float* __restrict__ x,         // (B, S, 128)
    const float* __restrict__ M,         // (64, 128)
    const float* __restrict__ Wres,      // (64, 128)
    const float* __restrict__ gamma,     // (64)
    const float* __restrict__ beta,      // (64)
    const float* __restrict__ P,         // (64, 64, 8)
    const int*   __restrict__ positions, // (S)
    float* __restrict__ out)             // (B, S, 64)
{
    const int s   = blockIdx.x;          // 0..511
    const int tid = threadIdx.x;

    __shared__ float xs[BATCH][IN_DIM];            // x rows
    __shared__ float xts[BATCH][OUT_DIM];          // normalized projections
    __shared__ float rs[BATCH][OUT_DIM];           // residual projections
    __shared__ float part[4][BATCH][OUT_DIM];      // phase-2 partials

    // cooperative load of both x rows: 256 floats, one per thread
    {
        const int b = tid >> 7;          // 0..1
        const int c = tid & 127;         // 0..127
        xs[b][c] = x[((size_t)b * SEQ + s) * IN_DIM + c];
    }
    const float k = (float)positions[s];
    __syncthreads();

    // ---- Phase 1: projections + LayerNorm (threads 0..127) ----
    if (tid < BATCH * OUT_DIM) {
        const int b = tid >> 6;          // == wave id (0 or 1)
        const int o = tid & 63;          // lane == output channel

        const float4* x4 = reinterpret_cast<const float4*>(xs[b]);
        const float4* m4 = reinterpret_cast<const float4*>(M    + (size_t)o * IN_DIM);
        const float4* w4 = reinterpret_cast<const float4*>(Wres + (size_t)o * IN_DIM);

        float macc = 0.f, racc = 0.f;
#pragma unroll
        for (int c = 0; c < IN_DIM / 4; ++c) {
            float4 xv = x4[c];
            float4 mv = m4[c];
            float4 wv = w4[c];
            macc += xv.x * mv.x + xv.y * mv.y + xv.z * mv.z + xv.w * mv.w;
            racc += xv.x * wv.x + xv.y * wv.y + xv.z * wv.z + xv.w * wv.w;
        }

        // mean over the 64 output channels (one wave == one batch row)
        float ssum = macc;
#pragma unroll
        for (int off = 32; off > 0; off >>= 1) ssum += __shfl_xor(ssum, off);
        const float mu = ssum * (1.0f / OUT_DIM);

        // two-pass variance for accuracy
        const float d = macc - mu;
        float v = d * d;
#pragma unroll
        for (int off = 32; off > 0; off >>= 1) v += __shfl_xor(v, off);
        const float var = v * (1.0f / OUT_DIM);

        xts[b][o] = d * rsqrtf(var + EPS) * gamma[o] + beta[o];
        rs[b][o]  = racc;
    }
    __syncthreads();

    // ---- Phase 2: W generation + contraction (all 256 threads) ----
    const int i   = tid & 63;
    const int grp = tid >> 6;            // 0..3, owns 16 j's

    float nk0 = 0.f, nk1 = 0.f;

#pragma unroll 4
    for (int jj = 0; jj < 16; ++jj) {
        const int j    = grp * 16 + jj;
        const int base = (i * OUT_DIM + j) * NUM_BASIS;     // flat (i,j,0)
        const float4* Pp = reinterpret_cast<const float4*>(P + base);
        const float4 p0 = Pp[0];
        const float4 p1 = Pp[1];
        const float basef = (float)(base + 2);              // period at g=0 (exact in f32)

        const float pv[8] = {p0.x, p0.y, p0.z, p0.w, p1.x, p1.y, p1.z, p1.w};
        float w = 0.f;
#pragma unroll
        for (int g = 0; g < NUM_BASIS; ++g) {
            const float period = basef + (float)g;
            const float inv    = __builtin_amdgcn_rcpf(period);   // ~1 ulp
            float t = k * inv;                                    // revolutions
            t = __builtin_amdgcn_fractf(t);                       // range-reduce
            w += pv[g] * __builtin_amdgcn_cosf(t);                // cos(2*pi*t)
        }
        nk0 += xts[0][j] * w;
        nk1 += xts[1][j] * w;
    }

    part[grp][0][i] = nk0;
    part[grp][1][i] = nk1;
    __syncthreads();

    // ---- Epilogue: reduce partials, add residual, store ----
    if (tid < BATCH * OUT_DIM) {
        const int b  = tid >> 6;
        const int ii = tid & 63;
        const float sum = part[0][b][ii] + part[1][b][ii] +
                          part[2][b][ii] + part[3][b][ii];
        const size_t idx = ((size_t)b * SEQ + s) * OUT_DIM + ii;
        out[idx] = sum + rs[b][ii];
    }
}

// ---------------------------------------------------------------------------
extern "C" void kernel_launch(void* const* d_in, const int* in_sizes, int n_in,
                              void* d_out, int out_size, void* d_ws, size_t ws_size,
                              hipStream_t stream)
{
    const float* x         = (const float*)d_in[0];
    const int*   positions = (const int*)d_in[1];
    const float* M         = (const float*)d_in[2];
    const float* P         = (const float*)d_in[3];
    const float* gamma     = (const float*)d_in[4];
    const float* beta      = (const float*)d_in[5];
    const float* Wres      = (const float*)d_in[6];
    float* out = (float*)d_out;

    hipLaunchKernelGGL(fused_layerts_kernel, dim3(SEQ), dim3(256), 0, stream,
                       x, M, Wres, gamma, beta, P, positions, out);
}

// Round 3
// 18.477 us; speedup vs baseline: 1.2321x; 1.1529x over previous
//
#include <hip/hip_runtime.h>
#include <hip/hip_bf16.h>

// Problem constants (fixed by the reference)
#define IN_DIM    128
#define OUT_DIM   64
#define NUM_BASIS 8
#define SEQ       512
#define BATCH     2
#define EPS       1e-5f
#define SX        2     // sequence positions per block

// ---------------------------------------------------------------------------
// Fully fused, 2 sequence positions per block: 256 blocks x 512 threads.
//
// Phase 1 (all 512 threads): half-row dot products for the M-projection and
//   the Wres residual projection, combined via LDS; LayerNorm via 64-lane
//   shfl butterfly (lane == output channel).
// Phase 2 (all 512 threads): i = tid&63, grp = tid>>6 owns 8 j's.
//   W[s,i,j] = sum_g P[i,j,g] * cos(2*pi*k_s / ((i*64+j)*8 + g + 2))
//   rcp(period) is s-independent -> computed once, cos per s (trans -25%).
//   P is read once per block for both s (L2 traffic halved).
// ---------------------------------------------------------------------------
__global__ __launch_bounds__(512) void fused_layerts_kernel(
    const float* __restrict__ x,         // (B, S, 128)
    const float* __restrict__ M,         // (64, 128)
    const float* __restrict__ Wres,      // (64, 128)
    const float* __restrict__ gamma,     // (64)
    const float* __restrict__ beta,      // (64)
    const float* __restrict__ P,         // (64, 64, 8)
    const int*   __restrict__ positions, // (S)
    float* __restrict__ out)             // (B, S, 64)
{
    const int s0  = blockIdx.x * SX;     // first seq position of this block
    const int tid = threadIdx.x;

    __shared__ float xs [SX][BATCH][IN_DIM];          // x rows (2 KB)
    __shared__ float xts[SX][BATCH][OUT_DIM];         // normalized projections
    __shared__ float rs [SX][BATCH][OUT_DIM];         // residual projections
    __shared__ float pm [2][SX * BATCH][OUT_DIM];     // phase-1 partials (M)
    __shared__ float pr [2][SX * BATCH][OUT_DIM];     // phase-1 partials (Wres)
    __shared__ float part[8][SX][BATCH][OUT_DIM];     // phase-2 partials (8 KB)

    // ---- load the 4 x-rows (SX*BATCH*IN_DIM = 512 floats, 1/thread) ----
    {
        const int row = tid >> 7;        // 0..3  = (sl, b)
        const int c   = tid & 127;
        const int b   = row & 1;
        const int sl  = row >> 1;
        xs[sl][b][c] = x[((size_t)b * SEQ + (s0 + sl)) * IN_DIM + c];
    }
    const float k0 = (float)positions[s0];
    const float k1 = (float)positions[s0 + 1];
    __syncthreads();

    // ---- Phase 1a: half-row dot products (all 512 threads) ----
    {
        const int o    = tid & 63;           // output channel
        const int r    = (tid >> 6) & 3;     // (sl<<1)|b
        const int half = tid >> 8;           // channel half 0..1
        const int b    = r & 1;
        const int sl   = r >> 1;

        const float4* x4 = reinterpret_cast<const float4*>(&xs[sl][b][half * 64]);
        const float4* m4 = reinterpret_cast<const float4*>(M    + (size_t)o * IN_DIM + half * 64);
        const float4* w4 = reinterpret_cast<const float4*>(Wres + (size_t)o * IN_DIM + half * 64);

        float macc = 0.f, racc = 0.f;
#pragma unroll
        for (int c = 0; c < 16; ++c) {
            float4 xv = x4[c];
            float4 mv = m4[c];
            float4 wv = w4[c];
            macc += xv.x * mv.x + xv.y * mv.y + xv.z * mv.z + xv.w * mv.w;
            racc += xv.x * wv.x + xv.y * wv.y + xv.z * wv.z + xv.w * wv.w;
        }
        pm[half][r][o] = macc;
        pr[half][r][o] = racc;
    }
    __syncthreads();

    // ---- Phase 1b: combine halves + LayerNorm (threads 0..255) ----
    if (tid < SX * BATCH * OUT_DIM) {
        const int o  = tid & 63;
        const int r  = tid >> 6;             // wave id == r, lanes == o
        const int b  = r & 1;
        const int sl = r >> 1;

        const float macc = pm[0][r][o] + pm[1][r][o];
        const float racc = pr[0][r][o] + pr[1][r][o];

        float ssum = macc;
#pragma unroll
        for (int off = 32; off > 0; off >>= 1) ssum += __shfl_xor(ssum, off);
        const float mu = ssum * (1.0f / OUT_DIM);

        const float d = macc - mu;
        float v = d * d;
#pragma unroll
        for (int off = 32; off > 0; off >>= 1) v += __shfl_xor(v, off);
        const float var = v * (1.0f / OUT_DIM);

        xts[sl][b][o] = d * rsqrtf(var + EPS) * gamma[o] + beta[o];
        rs [sl][b][o] = racc;
    }
    __syncthreads();

    // ---- Phase 2: W generation + contraction (all 512 threads) ----
    const int i   = tid & 63;
    const int grp = tid >> 6;                // 0..7, owns 8 j's

    float nk00 = 0.f, nk01 = 0.f, nk10 = 0.f, nk11 = 0.f;

#pragma unroll
    for (int jj = 0; jj < 8; ++jj) {
        const int j    = grp * 8 + jj;
        const int base = (i * OUT_DIM + j) * NUM_BASIS;   // flat (i,j,0)
        const float4* Pp = reinterpret_cast<const float4*>(P + base);
        const float4 p0 = Pp[0];
        const float4 p1 = Pp[1];
        const float basef = (float)(base + 2);            // period at g=0 (exact in f32)

        const float pv[8] = {p0.x, p0.y, p0.z, p0.w, p1.x, p1.y, p1.z, p1.w};
        float w0 = 0.f, w1 = 0.f;
#pragma unroll
        for (int g = 0; g < NUM_BASIS; ++g) {
            const float period = basef + (float)g;
            const float inv = __builtin_amdgcn_rcpf(period);     // s-independent
            float t0 = __builtin_amdgcn_fractf(k0 * inv);
            float t1 = __builtin_amdgcn_fractf(k1 * inv);
            w0 += pv[g] * __builtin_amdgcn_cosf(t0);             // cos(2*pi*t)
            w1 += pv[g] * __builtin_amdgcn_cosf(t1);
        }
        nk00 += xts[0][0][j] * w0;
        nk01 += xts[0][1][j] * w0;
        nk10 += xts[1][0][j] * w1;
        nk11 += xts[1][1][j] * w1;
    }

    part[grp][0][0][i] = nk00;
    part[grp][0][1][i] = nk01;
    part[grp][1][0][i] = nk10;
    part[grp][1][1][i] = nk11;
    __syncthreads();

    // ---- Epilogue: reduce partials, add residual, store (threads 0..255) ----
    if (tid < SX * BATCH * OUT_DIM) {
        const int o  = tid & 63;
        const int r  = tid >> 6;
        const int b  = r & 1;
        const int sl = r >> 1;

        float sum = 0.f;
#pragma unroll
        for (int gg = 0; gg < 8; ++gg) sum += part[gg][sl][b][o];

        const size_t idx = ((size_t)b * SEQ + (s0 + sl)) * OUT_DIM + o;
        out[idx] = sum + rs[sl][b][o];
    }
}

// ---------------------------------------------------------------------------
extern "C" void kernel_launch(void* const* d_in, const int* in_sizes, int n_in,
                              void* d_out, int out_size, void* d_ws, size_t ws_size,
                              hipStream_t stream)
{
    const float* x         = (const float*)d_in[0];
    const int*   positions = (const int*)d_in[1];
    const float* M         = (const float*)d_in[2];
    const float* P         = (const float*)d_in[3];
    const float* gamma     = (const float*)d_in[4];
    const float* beta      = (const float*)d_in[5];
    const float* Wres      = (const float*)d_in[6];
    float* out = (float*)d_out;

    hipLaunchKernelGGL(fused_layerts_kernel, dim3(SEQ / SX), dim3(512), 0, stream,
                       x, M, Wres, gamma, beta, P, positions, out);
}